// Round 1
// baseline (441.004 us; speedup 1.0000x reference)
//
#include <hip/hip_runtime.h>

// AdaMoeLayer: B=8,S=4096,D=512,E=8  -> T=32768 tokens
// out[t,f] = sum_e w[t,e] * ( x[t,:] @ W_exp[e] + b_exp[e] )[f]
// Fused as single GEMM: A'[T x 4160] * Bt^T, where
//   A'[t, e*512+d] = w[t,e]*x[t,d];  A'[t,4096+q] = w[t,q] (q<8), else 0
//   Bt[f, e*512+d] = W_exp[e,d,f];   Bt[f,4096+q] = b_exp[q,f] (q<8), else 0

#define T_TOKENS 32768
#define DDIM 512
#define KP 4160  // 8*512 + 64 (bias fold, zero-padded)

typedef __attribute__((ext_vector_type(8))) short short8;
typedef __attribute__((ext_vector_type(4))) float floatx4;

__device__ __forceinline__ unsigned short f2bf(float f) {
    unsigned int u = __float_as_uint(f);
    u += 0x7FFFu + ((u >> 16) & 1u);   // RNE
    return (unsigned short)(u >> 16);
}

__device__ __forceinline__ void async_copy16(const void* g, void* l) {
    __builtin_amdgcn_global_load_lds(
        (const __attribute__((address_space(1))) void*)g,
        (__attribute__((address_space(3))) void*)l, 16, 0, 0);
}

// ---------------- Kernel 1: gating (fp32 exact) -> wbuf[T,8] ----------------
__global__ __launch_bounds__(256) void gating_kernel(
    const float* __restrict__ x, const float* __restrict__ Wg,
    const float* __restrict__ bg, const float* __restrict__ Wt,
    const float* __restrict__ bt, float* __restrict__ wbuf)
{
    __shared__ float sW[512 * 12];  // [d][12]: e<8 gate cols, e==8 thr col, pad
    const int tid = threadIdx.x;
    for (int i = tid; i < 512 * 9; i += 256) {
        int d = i / 9, e = i - d * 9;
        sW[d * 12 + e] = (e < 8) ? Wg[d * 8 + e] : Wt[d];
    }
    __syncthreads();

    const int t = blockIdx.x * 256 + tid;
    float g[9];
#pragma unroll
    for (int e = 0; e < 9; ++e) g[e] = 0.f;

    const float4* xr = (const float4*)(x + (size_t)t * 512);
    for (int i = 0; i < 128; ++i) {
        float4 v = xr[i];
        float xv[4] = {v.x, v.y, v.z, v.w};
        const float* wp = &sW[(i * 4) * 12];
#pragma unroll
        for (int c = 0; c < 4; ++c) {
            const float* w = wp + c * 12;
#pragma unroll
            for (int e = 0; e < 9; ++e) g[e] = fmaf(xv[c], w[e], g[e]);
        }
    }
#pragma unroll
    for (int e = 0; e < 8; ++e) g[e] += bg[e];
    g[8] += bt[0];

    // softmax over 8
    float m = g[0];
#pragma unroll
    for (int e = 1; e < 8; ++e) m = fmaxf(m, g[e]);
    float s = 0.f;
    float p[8];
#pragma unroll
    for (int e = 0; e < 8; ++e) { p[e] = __expf(g[e] - m); s += p[e]; }
    const float inv = 1.f / s;
    const float thr = 0.25f / (1.f + __expf(-g[8]));

    float w8[8];
    float ws = 0.f;
#pragma unroll
    for (int e = 0; e < 8; ++e) {
        float a = p[e] * inv - thr;
        w8[e] = a > 0.f ? a : 0.f;
        ws += w8[e];
    }
    if (ws == 0.f) ws = 1.f;
    const float invw = 1.f / ws;

    float4 o0, o1;
    o0.x = w8[0] * invw; o0.y = w8[1] * invw; o0.z = w8[2] * invw; o0.w = w8[3] * invw;
    o1.x = w8[4] * invw; o1.y = w8[5] * invw; o1.z = w8[6] * invw; o1.w = w8[7] * invw;
    float4* op = (float4*)(wbuf + (size_t)t * 8);
    op[0] = o0;
    op[1] = o1;
}

// ------------- Kernel 2: build Bt[512][4160] bf16 (transpose W_exp) --------
__global__ __launch_bounds__(256) void build_bt(
    const float* __restrict__ Wexp, const float* __restrict__ bexp,
    unsigned short* __restrict__ Bt)
{
    __shared__ float tile[64][65];
    const int k0 = blockIdx.x * 64;
    const int n0 = blockIdx.y * 64;
    const int tid = threadIdx.x;
    const int r = tid >> 4, cq = tid & 15;
#pragma unroll
    for (int p = 0; p < 4; ++p) {
        const int rr = p * 16 + r;
        const int gk = k0 + rr;
        float4 v;
        if (gk < 4096)
            v = *(const float4*)(Wexp + (size_t)gk * 512 + n0 + cq * 4);
        else if (gk < 4104)
            v = *(const float4*)(bexp + (size_t)(gk - 4096) * 512 + n0 + cq * 4);
        else
            v = make_float4(0.f, 0.f, 0.f, 0.f);
        tile[rr][cq * 4 + 0] = v.x;
        tile[rr][cq * 4 + 1] = v.y;
        tile[rr][cq * 4 + 2] = v.z;
        tile[rr][cq * 4 + 3] = v.w;
    }
    __syncthreads();
    const int rn = tid >> 2;  // output row (n), 0..63
    const int kq = tid & 3;   // 16-wide k chunk
    alignas(16) unsigned short buf[16];
#pragma unroll
    for (int j = 0; j < 16; ++j) buf[j] = f2bf(tile[kq * 16 + j][rn]);
    unsigned short* dst = Bt + (size_t)(n0 + rn) * KP + k0 + kq * 16;
    *(uint4*)(dst) = *(const uint4*)(buf);
    *(uint4*)(dst + 8) = *(const uint4*)(buf + 8);
}

// ------------- Kernel 3: main fused GEMM, 128x128 tile, bf16 MFMA ----------
__global__ __launch_bounds__(256) void moe_gemm(
    const float* __restrict__ x, const float* __restrict__ wbuf,
    const unsigned short* __restrict__ Bt, float* __restrict__ out)
{
    __shared__ alignas(16) unsigned short As[128 * 64];  // [m][k]
    __shared__ alignas(16) unsigned short Bs[128 * 64];  // [n][k]

    const int tid = threadIdx.x;
    const int wave = tid >> 6;
    const int lane = tid & 63;
    const int wm = wave >> 1;  // 0..1
    const int wn = wave & 1;   // 0..1
    const int t0 = blockIdx.y * 128;
    const int n0 = blockIdx.x * 128;
    const int lm = lane & 15;
    const int lq = lane >> 4;

    floatx4 acc[4][4];
#pragma unroll
    for (int i = 0; i < 4; ++i)
#pragma unroll
        for (int j = 0; j < 4; ++j) acc[i][j] = (floatx4){0.f, 0.f, 0.f, 0.f};

    const int arow = tid >> 4;  // 0..15
    const int akq = tid & 15;   // float4 index along k
    const int brow = lane >> 3; // 0..7
    const int bk = lane & 7;    // 16B chunk along k

    for (int ks = 0; ks < 65; ++ks) {
        const int k0 = ks * 64;

        // --- B staging: async global->LDS (dwordx4), 4 instrs/wave
#pragma unroll
        for (int i = 0; i < 4; ++i) {
            const unsigned short* gp =
                Bt + (size_t)(n0 + wave * 32 + i * 8 + brow) * KP + k0 + bk * 8;
            async_copy16(gp, Bs + wave * 2048 + i * 512);
        }

        // --- A staging: fp32 x * w[t,e] -> bf16, ds_write_b64
        if (k0 < 4096) {
            const int e = k0 >> 9;
            const int d0 = (k0 & 511) + akq * 4;
#pragma unroll
            for (int p = 0; p < 8; ++p) {
                const int row = p * 16 + arow;
                const float w = wbuf[(size_t)(t0 + row) * 8 + e];
                const float4 v = *(const float4*)(x + (size_t)(t0 + row) * 512 + d0);
                uint2 pk;
                pk.x = (unsigned int)f2bf(v.x * w) | ((unsigned int)f2bf(v.y * w) << 16);
                pk.y = (unsigned int)f2bf(v.z * w) | ((unsigned int)f2bf(v.w * w) << 16);
                *(uint2*)(As + row * 64 + akq * 4) = pk;
            }
        } else {  // bias k-step: A' = w[t,q] for q<8 else 0
#pragma unroll
            for (int p = 0; p < 8; ++p) {
                const int row = p * 16 + arow;
                float vv[4];
#pragma unroll
                for (int c = 0; c < 4; ++c) {
                    const int q = akq * 4 + c;
                    vv[c] = (q < 8) ? wbuf[(size_t)(t0 + row) * 8 + q] : 0.f;
                }
                uint2 pk;
                pk.x = (unsigned int)f2bf(vv[0]) | ((unsigned int)f2bf(vv[1]) << 16);
                pk.y = (unsigned int)f2bf(vv[2]) | ((unsigned int)f2bf(vv[3]) << 16);
                *(uint2*)(As + row * 64 + akq * 4) = pk;
            }
        }
        __syncthreads();

        // --- compute: 2 k-subtiles of 32, 16 MFMAs each
#pragma unroll
        for (int kk = 0; kk < 2; ++kk) {
            const int koff = kk * 32 + lq * 8;
            short8 a[4], b[4];
#pragma unroll
            for (int i = 0; i < 4; ++i)
                a[i] = *(const short8*)(As + (wm * 64 + i * 16 + lm) * 64 + koff);
#pragma unroll
            for (int j = 0; j < 4; ++j)
                b[j] = *(const short8*)(Bs + (wn * 64 + j * 16 + lm) * 64 + koff);
#pragma unroll
            for (int i = 0; i < 4; ++i)
#pragma unroll
                for (int j = 0; j < 4; ++j)
                    acc[i][j] = __builtin_amdgcn_mfma_f32_16x16x32_bf16(
                        a[i], b[j], acc[i][j], 0, 0, 0);
        }
        __syncthreads();
    }

    // --- epilogue: C/D layout col=lane&15, row=(lane>>4)*4+reg
#pragma unroll
    for (int i = 0; i < 4; ++i) {
#pragma unroll
        for (int r = 0; r < 4; ++r) {
            const size_t t = (size_t)t0 + wm * 64 + i * 16 + lq * 4 + r;
            float* op = out + t * 512 + n0 + wn * 64 + lm;
#pragma unroll
            for (int j = 0; j < 4; ++j) op[j * 16] = acc[i][j][r];
        }
    }
}

extern "C" void kernel_launch(void* const* d_in, const int* in_sizes, int n_in,
                              void* d_out, int out_size, void* d_ws, size_t ws_size,
                              hipStream_t stream) {
    const float* x   = (const float*)d_in[0];
    const float* Wg  = (const float*)d_in[1];
    const float* bg  = (const float*)d_in[2];
    const float* Wt  = (const float*)d_in[3];
    const float* bt  = (const float*)d_in[4];
    const float* Wex = (const float*)d_in[5];
    const float* bex = (const float*)d_in[6];
    float* out = (float*)d_out;

    // ws layout: Bt bf16 [512][4160] = 4,259,840 B ; wbuf fp32 [32768][8] = 1 MB
    unsigned short* Bt = (unsigned short*)d_ws;
    float* wbuf = (float*)((char*)d_ws + (size_t)DDIM * KP * 2);

    gating_kernel<<<T_TOKENS / 256, 256, 0, stream>>>(x, Wg, bg, Wt, bt, wbuf);
    build_bt<<<dim3(KP / 64, DDIM / 64), 256, 0, stream>>>(Wex, bex, Bt);
    moe_gemm<<<dim3(DDIM / 128, T_TOKENS / 128), 256, 0, stream>>>(x, wbuf, Bt, out);
}

// Round 2
// 432.917 us; speedup vs baseline: 1.0187x; 1.0187x over previous
//
#include <hip/hip_runtime.h>

// AdaMoeLayer: B=8,S=4096,D=512,E=8  -> T=32768 tokens
// out[t,f] = sum_e w[t,e] * ( x[t,:] @ W_exp[e] + b_exp[e] )[f]
// Single GEMM: A'[T x 4160] * Bt^T where A'[t,e*512+d] = w[t,e]*x[t,d],
// bias folded as k=4096..4103 with A'=w[t,q], Bt rows = b_exp.
// LDS tiles XOR-swizzled (chunk ^= row&7) to kill 16-way read conflicts;
// B staging keeps global_load_lds by permuting the lane->global mapping.

#define T_TOKENS 32768
#define DDIM 512
#define KP 4160  // 8*512 + 64 (bias fold, zero-padded)

typedef __attribute__((ext_vector_type(8))) short short8;
typedef __attribute__((ext_vector_type(4))) float floatx4;
typedef __bf16 bf16x2 __attribute__((ext_vector_type(2)));

__device__ __forceinline__ unsigned short f2bf(float f) {
    unsigned int u = __float_as_uint(f);
    u += 0x7FFFu + ((u >> 16) & 1u);   // RNE
    return (unsigned short)(u >> 16);
}

__device__ __forceinline__ unsigned int pk2(float a, float b) {
#if __has_builtin(__builtin_amdgcn_cvt_pk_bf16_f32)
    bf16x2 v = __builtin_amdgcn_cvt_pk_bf16_f32(a, b);
    return __builtin_bit_cast(unsigned int, v);
#else
    return (unsigned int)f2bf(a) | ((unsigned int)f2bf(b) << 16);
#endif
}

__device__ __forceinline__ void async_copy16(const void* g, void* l) {
    __builtin_amdgcn_global_load_lds(
        (const __attribute__((address_space(1))) void*)g,
        (__attribute__((address_space(3))) void*)l, 16, 0, 0);
}

// ---------------- Kernel 1: gating (fp32) -> wbuf[T,8] ----------------
// 4 threads per token, shfl-xor reduce; grid = T/64 = 512 blocks.
__global__ __launch_bounds__(256) void gating_kernel(
    const float* __restrict__ x, const float* __restrict__ Wg,
    const float* __restrict__ bg, const float* __restrict__ Wt,
    const float* __restrict__ bt, float* __restrict__ wbuf)
{
    __shared__ float sW[512 * 12];  // [d][12]: e<8 gate cols, e==8 thr col
    const int tid = threadIdx.x;
    for (int i = tid; i < 512 * 9; i += 256) {
        int d = i / 9, e = i - d * 9;
        sW[d * 12 + e] = (e < 8) ? Wg[d * 8 + e] : Wt[d];
    }
    __syncthreads();

    const int t = blockIdx.x * 64 + (tid >> 2);
    const int q = tid & 3;
    float g[9];
#pragma unroll
    for (int e = 0; e < 9; ++e) g[e] = 0.f;

    const float4* xr = (const float4*)(x + (size_t)t * 512 + q * 128);
    for (int i = 0; i < 32; ++i) {
        float4 v = xr[i];
        float xv[4] = {v.x, v.y, v.z, v.w};
        const float* wp = &sW[(q * 128 + i * 4) * 12];
#pragma unroll
        for (int c = 0; c < 4; ++c) {
            const float* w = wp + c * 12;
#pragma unroll
            for (int e = 0; e < 9; ++e) g[e] = fmaf(xv[c], w[e], g[e]);
        }
    }
    // reduce partials across the 4 lanes of this token
#pragma unroll
    for (int e = 0; e < 9; ++e) {
        g[e] += __shfl_xor(g[e], 1);
        g[e] += __shfl_xor(g[e], 2);
    }
    if (q == 0) {
#pragma unroll
        for (int e = 0; e < 8; ++e) g[e] += bg[e];
        g[8] += bt[0];
        float m = g[0];
#pragma unroll
        for (int e = 1; e < 8; ++e) m = fmaxf(m, g[e]);
        float s = 0.f;
        float p[8];
#pragma unroll
        for (int e = 0; e < 8; ++e) { p[e] = __expf(g[e] - m); s += p[e]; }
        const float inv = 1.f / s;
        const float thr = 0.25f / (1.f + __expf(-g[8]));
        float w8[8];
        float ws = 0.f;
#pragma unroll
        for (int e = 0; e < 8; ++e) {
            float a = p[e] * inv - thr;
            w8[e] = a > 0.f ? a : 0.f;
            ws += w8[e];
        }
        if (ws == 0.f) ws = 1.f;
        const float invw = 1.f / ws;
        float4 o0, o1;
        o0.x = w8[0] * invw; o0.y = w8[1] * invw; o0.z = w8[2] * invw; o0.w = w8[3] * invw;
        o1.x = w8[4] * invw; o1.y = w8[5] * invw; o1.z = w8[6] * invw; o1.w = w8[7] * invw;
        float4* op = (float4*)(wbuf + (size_t)t * 8);
        op[0] = o0;
        op[1] = o1;
    }
}

// ------------- Kernel 2: build Bt[512][4160] bf16 (transpose W_exp) --------
__global__ __launch_bounds__(256) void build_bt(
    const float* __restrict__ Wexp, const float* __restrict__ bexp,
    unsigned short* __restrict__ Bt)
{
    __shared__ float tile[64][65];
    const int k0 = blockIdx.x * 64;
    const int n0 = blockIdx.y * 64;
    const int tid = threadIdx.x;
    const int r = tid >> 4, cq = tid & 15;
#pragma unroll
    for (int p = 0; p < 4; ++p) {
        const int rr = p * 16 + r;
        const int gk = k0 + rr;
        float4 v;
        if (gk < 4096)
            v = *(const float4*)(Wexp + (size_t)gk * 512 + n0 + cq * 4);
        else if (gk < 4104)
            v = *(const float4*)(bexp + (size_t)(gk - 4096) * 512 + n0 + cq * 4);
        else
            v = make_float4(0.f, 0.f, 0.f, 0.f);
        tile[rr][cq * 4 + 0] = v.x;
        tile[rr][cq * 4 + 1] = v.y;
        tile[rr][cq * 4 + 2] = v.z;
        tile[rr][cq * 4 + 3] = v.w;
    }
    __syncthreads();
    const int rn = tid >> 2;  // output row (n), 0..63
    const int kq = tid & 3;   // 16-wide k chunk
    alignas(16) unsigned short buf[16];
#pragma unroll
    for (int j = 0; j < 16; ++j) buf[j] = f2bf(tile[kq * 16 + j][rn]);
    unsigned short* dst = Bt + (size_t)(n0 + rn) * KP + k0 + kq * 16;
    *(uint4*)(dst) = *(const uint4*)(buf);
    *(uint4*)(dst + 8) = *(const uint4*)(buf + 8);
}

// ------------- Kernel 3: main fused GEMM, 128x128 tile, bf16 MFMA ----------
// LDS layout (both tiles): element (row,k) lives at
//   row*64 + ((k/8 ^ (row&7))*8) + (k%8)   [shorts]
__global__ __launch_bounds__(256) void moe_gemm(
    const float* __restrict__ x, const float* __restrict__ wbuf,
    const unsigned short* __restrict__ Bt, float* __restrict__ out)
{
    __shared__ alignas(16) unsigned short As[128 * 64];
    __shared__ alignas(16) unsigned short Bs[128 * 64];
    __shared__ float sWb[128 * 8];  // gate weights for this token tile

    const int tid = threadIdx.x;
    const int wave = tid >> 6;
    const int lane = tid & 63;
    const int wm = wave >> 1;
    const int wn = wave & 1;
    const int lm = lane & 15;
    const int lq = lane >> 4;

    // XCD-aware swizzle: each XCD owns one n-tile (Bt tile stays in its L2);
    // the 4 n-tiles of a token tile run concurrently (x via LLC).
    const int id = blockIdx.x + 4 * blockIdx.y;  // grid = (4, 256)
    const int xcd = id & 7;
    const int n0 = (xcd & 3) * 128;
    const int t0 = ((id >> 3) + (xcd >> 2) * 128) * 128;

    // stage gate weights once: 128 tokens x 8 = 256 float4
    ((float4*)sWb)[tid] = ((const float4*)(wbuf + (size_t)t0 * 8))[tid];

    floatx4 acc[4][4];
#pragma unroll
    for (int i = 0; i < 4; ++i)
#pragma unroll
        for (int j = 0; j < 4; ++j) acc[i][j] = (floatx4){0.f, 0.f, 0.f, 0.f};

    const int rb = tid >> 3;   // A-staging: row base 0..31
    const int ac = tid & 7;    // A-staging: 16B chunk 0..7
    const int brow = lane >> 3;       // B-staging row within group of 8
    const int cg = (lane & 7) ^ brow; // lane->global chunk permutation

    __syncthreads();  // sWb visible

    for (int ks = 0; ks < 65; ++ks) {
        const int k0 = ks * 64;

        // --- B staging: async global->LDS, lane-permuted so data lands swizzled
#pragma unroll
        for (int i = 0; i < 4; ++i) {
            const unsigned short* gp =
                Bt + (size_t)(n0 + wave * 32 + i * 8 + brow) * KP + k0 + cg * 8;
            async_copy16(gp, Bs + wave * 2048 + i * 512);
        }

        // --- A staging: fp32 x * w -> bf16, one ds_write_b128 per row-chunk
        if (k0 < 4096) {
            const int e = k0 >> 9;
            const int d0 = (k0 & 511) + ac * 8;
#pragma unroll
            for (int p = 0; p < 4; ++p) {
                const int row = p * 32 + rb;
                const float w = sWb[row * 8 + e];
                const float* xp = x + (size_t)(t0 + row) * 512 + d0;
                const float4 v0 = *(const float4*)(xp);
                const float4 v1 = *(const float4*)(xp + 4);
                uint4 pk;
                pk.x = pk2(v0.x * w, v0.y * w);
                pk.y = pk2(v0.z * w, v0.w * w);
                pk.z = pk2(v1.x * w, v1.y * w);
                pk.w = pk2(v1.z * w, v1.w * w);
                *(uint4*)(As + row * 64 + ((ac ^ (row & 7)) << 3)) = pk;
            }
        } else {  // bias k-step: A' = w[t,q] for q<8 else 0
#pragma unroll
            for (int p = 0; p < 4; ++p) {
                const int row = p * 32 + rb;
                uint4 pk = {0u, 0u, 0u, 0u};
                if (ac == 0) {
                    pk.x = pk2(sWb[row * 8 + 0], sWb[row * 8 + 1]);
                    pk.y = pk2(sWb[row * 8 + 2], sWb[row * 8 + 3]);
                    pk.z = pk2(sWb[row * 8 + 4], sWb[row * 8 + 5]);
                    pk.w = pk2(sWb[row * 8 + 6], sWb[row * 8 + 7]);
                }
                *(uint4*)(As + row * 64 + ((ac ^ (row & 7)) << 3)) = pk;
            }
        }
        __syncthreads();

        // --- compute: 2 k-subtiles of 32, 16 MFMAs each
#pragma unroll
        for (int kk = 0; kk < 2; ++kk) {
            const int ch = kk * 4 + lq;  // 16B chunk index along k
            short8 a[4], b[4];
#pragma unroll
            for (int i = 0; i < 4; ++i) {
                const int row = wm * 64 + i * 16 + lm;
                a[i] = *(const short8*)(As + row * 64 + ((ch ^ (row & 7)) << 3));
            }
#pragma unroll
            for (int j = 0; j < 4; ++j) {
                const int row = wn * 64 + j * 16 + lm;
                b[j] = *(const short8*)(Bs + row * 64 + ((ch ^ (row & 7)) << 3));
            }
#pragma unroll
            for (int i = 0; i < 4; ++i)
#pragma unroll
                for (int j = 0; j < 4; ++j)
                    acc[i][j] = __builtin_amdgcn_mfma_f32_16x16x32_bf16(
                        a[i], b[j], acc[i][j], 0, 0, 0);
        }
        __syncthreads();
    }

    // --- epilogue: C/D layout col=lane&15, row=(lane>>4)*4+reg
#pragma unroll
    for (int i = 0; i < 4; ++i) {
#pragma unroll
        for (int r = 0; r < 4; ++r) {
            const size_t t = (size_t)t0 + wm * 64 + i * 16 + lq * 4 + r;
            float* op = out + t * 512 + n0 + wn * 64 + lm;
#pragma unroll
            for (int j = 0; j < 4; ++j) op[j * 16] = acc[i][j][r];
        }
    }
}

extern "C" void kernel_launch(void* const* d_in, const int* in_sizes, int n_in,
                              void* d_out, int out_size, void* d_ws, size_t ws_size,
                              hipStream_t stream) {
    const float* x   = (const float*)d_in[0];
    const float* Wg  = (const float*)d_in[1];
    const float* bg  = (const float*)d_in[2];
    const float* Wt  = (const float*)d_in[3];
    const float* bt  = (const float*)d_in[4];
    const float* Wex = (const float*)d_in[5];
    const float* bex = (const float*)d_in[6];
    float* out = (float*)d_out;

    // ws layout: Bt bf16 [512][4160] = 4,259,840 B ; wbuf fp32 [32768][8] = 1 MB
    unsigned short* Bt = (unsigned short*)d_ws;
    float* wbuf = (float*)((char*)d_ws + (size_t)DDIM * KP * 2);

    gating_kernel<<<T_TOKENS / 64, 256, 0, stream>>>(x, Wg, bg, Wt, bt, wbuf);
    build_bt<<<dim3(KP / 64, DDIM / 64), 256, 0, stream>>>(Wex, bex, Bt);
    moe_gemm<<<dim3(DDIM / 128, T_TOKENS / 128), 256, 0, stream>>>(x, wbuf, Bt, out);
}

// Round 3
// 383.860 us; speedup vs baseline: 1.1489x; 1.1278x over previous
//
#include <hip/hip_runtime.h>

// AdaMoeLayer: B=8,S=4096,D=512,E=8  -> T=32768 tokens
// out[t,f] = sum_e w[t,e] * ( x[t,:] @ W_exp[e] + b_exp[e] )[f]
// Round 3: w applied to ACCUMULATOR at expert boundaries (linear), so both
// A (bf16 x) and B (transposed W_exp) stage via global_load_lds width-16.
// Bias enters as the MFMA accumulator init (splat per column). Expert loop
// outer: 8 experts x 8 k-steps of 64.

#define T_TOKENS 32768
#define DDIM 512
#define KDIM 4096

typedef __attribute__((ext_vector_type(8))) short short8;
typedef __attribute__((ext_vector_type(4))) float floatx4;
typedef __bf16 bf16x2 __attribute__((ext_vector_type(2)));

__device__ __forceinline__ unsigned short f2bf(float f) {
    unsigned int u = __float_as_uint(f);
    u += 0x7FFFu + ((u >> 16) & 1u);   // RNE
    return (unsigned short)(u >> 16);
}

__device__ __forceinline__ unsigned int pk2(float a, float b) {
#if __has_builtin(__builtin_amdgcn_cvt_pk_bf16_f32)
    bf16x2 v = __builtin_amdgcn_cvt_pk_bf16_f32(a, b);
    return __builtin_bit_cast(unsigned int, v);
#else
    return (unsigned int)f2bf(a) | ((unsigned int)f2bf(b) << 16);
#endif
}

__device__ __forceinline__ void async_copy16(const void* g, void* l) {
    __builtin_amdgcn_global_load_lds(
        (const __attribute__((address_space(1))) void*)g,
        (__attribute__((address_space(3))) void*)l, 16, 0, 0);
}

// ------- Kernel 1: gating (fp32) -> wbuf[T,8]  +  x -> bf16 Xbf[T,512] ------
// 4 threads per token, shfl-xor reduce; grid = T/64 = 512 blocks.
__global__ __launch_bounds__(256) void gating_cvt(
    const float* __restrict__ x, const float* __restrict__ Wg,
    const float* __restrict__ bg, const float* __restrict__ Wt,
    const float* __restrict__ bt, float* __restrict__ wbuf,
    unsigned short* __restrict__ Xbf)
{
    __shared__ float sW[512 * 12];  // [d][12]: e<8 gate cols, e==8 thr col
    const int tid = threadIdx.x;
    for (int i = tid; i < 512 * 9; i += 256) {
        int d = i / 9, e = i - d * 9;
        sW[d * 12 + e] = (e < 8) ? Wg[d * 8 + e] : Wt[d];
    }
    __syncthreads();

    const int t = blockIdx.x * 64 + (tid >> 2);
    const int q = tid & 3;
    float g[9];
#pragma unroll
    for (int e = 0; e < 9; ++e) g[e] = 0.f;

    const float4* xr = (const float4*)(x + (size_t)t * 512 + q * 128);
    for (int i = 0; i < 32; ++i) {
        float4 v = xr[i];
        float xv[4] = {v.x, v.y, v.z, v.w};
        const float* wp = &sW[(q * 128 + i * 4) * 12];
#pragma unroll
        for (int c = 0; c < 4; ++c) {
            const float* w = wp + c * 12;
#pragma unroll
            for (int e = 0; e < 9; ++e) g[e] = fmaf(xv[c], w[e], g[e]);
        }
    }
#pragma unroll
    for (int e = 0; e < 9; ++e) {
        g[e] += __shfl_xor(g[e], 1);
        g[e] += __shfl_xor(g[e], 2);
    }
    if (q == 0) {
#pragma unroll
        for (int e = 0; e < 8; ++e) g[e] += bg[e];
        g[8] += bt[0];
        float m = g[0];
#pragma unroll
        for (int e = 1; e < 8; ++e) m = fmaxf(m, g[e]);
        float s = 0.f;
        float p[8];
#pragma unroll
        for (int e = 0; e < 8; ++e) { p[e] = __expf(g[e] - m); s += p[e]; }
        const float inv = 1.f / s;
        const float thr = 0.25f / (1.f + __expf(-g[8]));
        float w8[8];
        float ws = 0.f;
#pragma unroll
        for (int e = 0; e < 8; ++e) {
            float a = p[e] * inv - thr;
            w8[e] = a > 0.f ? a : 0.f;
            ws += w8[e];
        }
        if (ws == 0.f) ws = 1.f;
        const float invw = 1.f / ws;
        float4 o0, o1;
        o0.x = w8[0] * invw; o0.y = w8[1] * invw; o0.z = w8[2] * invw; o0.w = w8[3] * invw;
        o1.x = w8[4] * invw; o1.y = w8[5] * invw; o1.z = w8[6] * invw; o1.w = w8[7] * invw;
        float4* op = (float4*)(wbuf + (size_t)t * 8);
        op[0] = o0;
        op[1] = o1;
    }

    // conversion pass: this block's 64 tokens = 32768 floats, coalesced (L2-hot)
    const size_t base = (size_t)blockIdx.x * 64 * 512;
    const float4* xs = (const float4*)(x + base);
    uint2* xd = (uint2*)(Xbf + base);
#pragma unroll 4
    for (int it = 0; it < 32; ++it) {
        float4 v = xs[it * 256 + tid];
        uint2 pk;
        pk.x = pk2(v.x, v.y);
        pk.y = pk2(v.z, v.w);
        xd[it * 256 + tid] = pk;
    }
}

// ------------- Kernel 2: build Bt[512][4096] bf16 (transpose W_exp) --------
__global__ __launch_bounds__(256) void build_bt(
    const float* __restrict__ Wexp, unsigned short* __restrict__ Bt)
{
    __shared__ float tile[64][65];
    const int k0 = blockIdx.x * 64;
    const int n0 = blockIdx.y * 64;
    const int tid = threadIdx.x;
    const int r = tid >> 4, cq = tid & 15;
#pragma unroll
    for (int p = 0; p < 4; ++p) {
        const int rr = p * 16 + r;
        const float4 v = *(const float4*)(Wexp + (size_t)(k0 + rr) * 512 + n0 + cq * 4);
        tile[rr][cq * 4 + 0] = v.x;
        tile[rr][cq * 4 + 1] = v.y;
        tile[rr][cq * 4 + 2] = v.z;
        tile[rr][cq * 4 + 3] = v.w;
    }
    __syncthreads();
    const int rn = tid >> 2;  // output row (n), 0..63
    const int kq = tid & 3;   // 16-wide k chunk
    alignas(16) unsigned short buf[16];
#pragma unroll
    for (int j = 0; j < 16; ++j) buf[j] = f2bf(tile[kq * 16 + j][rn]);
    unsigned short* dst = Bt + (size_t)(n0 + rn) * KDIM + k0 + kq * 16;
    *(uint4*)(dst) = *(const uint4*)(buf);
    *(uint4*)(dst + 8) = *(const uint4*)(buf + 8);
}

// ------------- Kernel 3: main GEMM, 128x64 block tile, expert-outer --------
// LDS tiles XOR-swizzled: element (row,k) at row*64 + ((k/8 ^ (row&7))*8)+k%8.
// Both operands staged by global_load_lds with the lane->global chunk
// permutation cg = (lane&7)^(lane>>3) so data lands pre-swizzled.
__global__ __launch_bounds__(256, 4) void moe_gemm(
    const unsigned short* __restrict__ Xbf, const float* __restrict__ wbuf,
    const float* __restrict__ bexp, const unsigned short* __restrict__ Bt,
    float* __restrict__ out)
{
    __shared__ alignas(16) unsigned short As[128 * 64];  // 16 KB
    __shared__ alignas(16) unsigned short Bs[64 * 64];   // 8 KB
    __shared__ float sWb[128 * 8];                       // 4 KB gate weights
    __shared__ float sBb[8 * 64];                        // 2 KB bias slice

    const int tid = threadIdx.x;
    const int wave = tid >> 6;
    const int lane = tid & 63;
    const int wm = wave >> 1;   // 0..1: 64-row group
    const int wn = wave & 1;    // 0..1: 32-col group
    const int lm = lane & 15;
    const int lq = lane >> 4;
    const int brow = lane >> 3;
    const int cg = (lane & 7) ^ brow;  // lane->global chunk permutation

    // XCD co-location: hw XCD = lin%8. For XCD g, j=lin>>3 enumerates
    // (t_local = j>>3, n_tile = j&7): the 8 n-blocks of a t-tile are
    // consecutive j (concurrent, share the 128KB x-slice in that XCD's L2).
    const int lin = blockIdx.x;
    const int g = lin & 7;
    const int j_ = lin >> 3;
    const int t0 = (g * 32 + (j_ >> 3)) * 128;
    const int n0 = (j_ & 7) * 64;

    ((float4*)sWb)[tid] = ((const float4*)(wbuf + (size_t)t0 * 8))[tid];
    if (tid < 128) {
        const int e = tid >> 4, c4 = tid & 15;
        ((float4*)sBb)[tid] = *(const float4*)(bexp + (size_t)e * 512 + n0 + c4 * 4);
    }
    __syncthreads();

    floatx4 acc[4][2];
#pragma unroll
    for (int i = 0; i < 4; ++i) {
        acc[i][0] = (floatx4){0.f, 0.f, 0.f, 0.f};
        acc[i][1] = (floatx4){0.f, 0.f, 0.f, 0.f};
    }

    for (int e = 0; e < 8; ++e) {
        // tmp starts as the bias (exact fp32 accumulate through MFMA)
        const float bb0 = sBb[e * 64 + wn * 32 + lm];
        const float bb1 = sBb[e * 64 + wn * 32 + 16 + lm];
        floatx4 tmp[4][2];
#pragma unroll
        for (int i = 0; i < 4; ++i) {
            tmp[i][0] = (floatx4){bb0, bb0, bb0, bb0};
            tmp[i][1] = (floatx4){bb1, bb1, bb1, bb1};
        }

        for (int ks = 0; ks < 8; ++ks) {
            const int k0 = e * 512 + ks * 64;
            const int d0 = ks * 64 + cg * 8;  // x column (k mod 512)

            // A staging: 4 DMA/wave, rows wave*32 .. wave*32+31
#pragma unroll
            for (int i = 0; i < 4; ++i) {
                const int row = wave * 32 + i * 8 + brow;
                async_copy16(Xbf + (size_t)(t0 + row) * 512 + d0,
                             As + (wave * 32 + i * 8) * 64);
            }
            // B staging: 2 DMA/wave, rows wave*16 .. wave*16+15
#pragma unroll
            for (int i = 0; i < 2; ++i) {
                const int row = wave * 16 + i * 8 + brow;
                async_copy16(Bt + (size_t)(n0 + row) * KDIM + k0 + cg * 8,
                             Bs + (wave * 16 + i * 8) * 64);
            }
            __syncthreads();

#pragma unroll
            for (int kk = 0; kk < 2; ++kk) {
                const int ch = kk * 4 + lq;
                short8 a[4], b[2];
#pragma unroll
                for (int i = 0; i < 4; ++i) {
                    const int row = wm * 64 + i * 16 + lm;
                    a[i] = *(const short8*)(As + row * 64 + ((ch ^ (row & 7)) << 3));
                }
#pragma unroll
                for (int j = 0; j < 2; ++j) {
                    const int row = wn * 32 + j * 16 + lm;
                    b[j] = *(const short8*)(Bs + row * 64 + ((ch ^ (row & 7)) << 3));
                }
#pragma unroll
                for (int i = 0; i < 4; ++i)
#pragma unroll
                    for (int j = 0; j < 2; ++j)
                        tmp[i][j] = __builtin_amdgcn_mfma_f32_16x16x32_bf16(
                            a[i], b[j], tmp[i][j], 0, 0, 0);
            }
            __syncthreads();
        }

        // fold: acc += w[t,e] * tmp   (w in fp32, per-row)
#pragma unroll
        for (int i = 0; i < 4; ++i)
#pragma unroll
            for (int r = 0; r < 4; ++r) {
                const float wv = sWb[(wm * 64 + i * 16 + lq * 4 + r) * 8 + e];
                acc[i][0][r] = fmaf(wv, tmp[i][0][r], acc[i][0][r]);
                acc[i][1][r] = fmaf(wv, tmp[i][1][r], acc[i][1][r]);
            }
    }

    // epilogue: C/D layout col=lane&15, row=(lane>>4)*4+reg
#pragma unroll
    for (int i = 0; i < 4; ++i)
#pragma unroll
        for (int r = 0; r < 4; ++r) {
            const size_t t = (size_t)t0 + wm * 64 + i * 16 + lq * 4 + r;
            float* op = out + t * 512 + n0 + wn * 32 + lm;
            op[0] = acc[i][0][r];
            op[16] = acc[i][1][r];
        }
}

extern "C" void kernel_launch(void* const* d_in, const int* in_sizes, int n_in,
                              void* d_out, int out_size, void* d_ws, size_t ws_size,
                              hipStream_t stream) {
    const float* x   = (const float*)d_in[0];
    const float* Wg  = (const float*)d_in[1];
    const float* bg  = (const float*)d_in[2];
    const float* Wt  = (const float*)d_in[3];
    const float* bt  = (const float*)d_in[4];
    const float* Wex = (const float*)d_in[5];
    const float* bex = (const float*)d_in[6];
    float* out = (float*)d_out;

    // ws layout: Xbf bf16 [32768][512] = 32 MB; Bt bf16 [512][4096] = 4 MB;
    //            wbuf fp32 [32768][8] = 1 MB.  Total 37 MB.
    unsigned short* Xbf = (unsigned short*)d_ws;
    unsigned short* Bt  = (unsigned short*)((char*)d_ws + (size_t)T_TOKENS * DDIM * 2);
    float* wbuf = (float*)((char*)d_ws + (size_t)T_TOKENS * DDIM * 2
                                       + (size_t)DDIM * KDIM * 2);

    gating_cvt<<<T_TOKENS / 64, 256, 0, stream>>>(x, Wg, bg, Wt, bt, wbuf, Xbf);
    build_bt<<<dim3(KDIM / 64, DDIM / 64), 256, 0, stream>>>(Wex, Bt);
    moe_gemm<<<2048, 256, 0, stream>>>(Xbf, wbuf, bex, Bt, out);
}